// Round 6
// baseline (386.929 us; speedup 1.0000x reference)
//
#include <hip/hip_runtime.h>

#define N_TOT   500000
#define M_Q     1024
#define QB      16
#define NSPLIT  16
#define CAND_MAX 8192

#define ARGMIN_BLKS 1024            // 64 query-tiles x 16 N-splits
#define HIST_BLKS   32
#define USAGE_BLKS  64
#define CROWS       16              // rows per copy block
#define COPY_BLKS   (N_TOT / CROWS) // 31250
#define MEGA_BLKS   (ARGMIN_BLKS + HIST_BLKS + USAGE_BLKS + COPY_BLKS)
#define HIST_CHUNK  (N_TOT / HIST_BLKS)   // 15625

static const unsigned OUT_ROWS  = 259u * (unsigned)N_TOT;     // 129,500,000
static const unsigned OUT_USAGE = OUT_ROWS;
static const unsigned OUT_IDX   = OUT_ROWS + (unsigned)N_TOT; // 130,000,000

// ---- ws layout (bytes) ----
#define WS_PARTKEY 0                 // M*NSPLIT f32 = 65536
#define WS_PARTIDX 65536             // M*NSPLIT i32 = 65536
#define WS_HISTP   131072            // 32*1024 i32  = 131072 (plain stores, no zeroing)

// =====================  MEGA: argmin || hist || usage-copy || row-copy ==============
__global__ __launch_bounds__(256) void k_mega(
    const float* __restrict__ pts,  const float* __restrict__ mpts,
    const float* __restrict__ mdesc, const int* __restrict__ usage,
    float* __restrict__ out,
    float* __restrict__ partKey, int* __restrict__ partIdx,
    int* __restrict__ histPart)
{
    __shared__ int smem[1024];            // 4 KB, used by argmin/hist roles only
    const int b   = blockIdx.x;
    const int tid = threadIdx.x;

    if (b < ARGMIN_BLKS) {
        // ---------------- argmin role (math identical since R1: absmax 0) ----------
        const int qb = b & 63;
        const int ns = b >> 6;
        const int qbase = qb * QB;
        const int chunk = N_TOT / NSPLIT;   // 31250
        const int n0 = ns * chunk;
        const int n1 = n0 + chunk;

        float* qs = (float*)smem;           // 48 floats
        float* wk = (float*)smem + 64;      // [4][16]
        int*   wi = smem + 192;             // [4][16]
        if (tid < QB * 3) qs[tid] = pts[qbase * 3 + tid];
        __syncthreads();

        float qx[QB], qy[QB], qz[QB];
#pragma unroll
        for (int i = 0; i < QB; i++) { qx[i] = qs[3*i]; qy[i] = qs[3*i+1]; qz[i] = qs[3*i+2]; }

        float bk[QB]; int bi[QB];
#pragma unroll
        for (int i = 0; i < QB; i++) { bk[i] = INFINITY; bi[i] = 0x7fffffff; }

        for (int n = n0 + tid; n < n1; n += 256) {
            float x = mpts[3*n+0], y = mpts[3*n+1], z = mpts[3*n+2];
            float h = 0.5f * (x*x + y*y + z*z);
#pragma unroll
            for (int i = 0; i < QB; i++) {
                float key = h - x*qx[i] - y*qy[i] - z*qz[i];
                bool lt = key < bk[i];      // strict < + ascending n => first-min kept
                bk[i] = lt ? key : bk[i];
                bi[i] = lt ? n   : bi[i];
            }
        }

        const int lane = tid & 63;
        const int wv   = tid >> 6;
#pragma unroll
        for (int off = 32; off > 0; off >>= 1) {
#pragma unroll
            for (int i = 0; i < QB; i++) {
                float ok = __shfl_down(bk[i], off, 64);
                int   oi = __shfl_down(bi[i], off, 64);
                if (ok < bk[i] || (ok == bk[i] && oi < bi[i])) { bk[i] = ok; bi[i] = oi; }
            }
        }
        if (lane == 0) {
#pragma unroll
            for (int i = 0; i < QB; i++) { wk[wv*QB + i] = bk[i]; wi[wv*QB + i] = bi[i]; }
        }
        __syncthreads();
        if (tid < QB) {
            float k = wk[tid]; int ix = wi[tid];
#pragma unroll
            for (int w = 1; w < 4; w++) {
                float ok = wk[w*QB + tid]; int oi = wi[w*QB + tid];
                if (ok < k || (ok == k && oi < ix)) { k = ok; ix = oi; }
            }
            partKey[(qbase + tid) * NSPLIT + ns] = k;
            partIdx[(qbase + tid) * NSPLIT + ns] = ix;
        }
    } else if (b < ARGMIN_BLKS + HIST_BLKS) {
        // ---------------- hist role: per-block partial histogram -------------------
        const int hb = b - ARGMIN_BLKS;
        const int r0 = hb * HIST_CHUNK;
        const int r1 = r0 + HIST_CHUNK;
#pragma unroll
        for (int i = 0; i < 4; i++) smem[tid + i * 256] = 0;
        __syncthreads();
        for (int n = r0 + tid; n < r1; n += 256) {
            unsigned v = (unsigned)usage[n];
            if (v > 1023u) v = 1023u;
            atomicAdd(&smem[v], 1);
        }
        __syncthreads();
#pragma unroll
        for (int i = 0; i < 4; i++) {
            int bin = tid + i * 256;
            histPart[hb * 1024 + bin] = smem[bin];
        }
    } else if (b < ARGMIN_BLKS + HIST_BLKS + USAGE_BLKS) {
        // ---------------- usage-as-float role (int4 -> float4) ---------------------
        const int ub = b - ARGMIN_BLKS - HIST_BLKS;
        const int4* u4 = (const int4*)usage;
        float4* o4 = (float4*)(out + OUT_USAGE);    // offset %4==0: 16B-aligned
        const int TOT4 = N_TOT / 4;                 // 125000
        for (int g = ub * 256 + tid; g < TOT4; g += USAGE_BLKS * 256) {
            int4 u = u4[g];
            o4[g] = make_float4((float)u.x, (float)u.y, (float)u.z, (float)u.w);
        }
    } else {
        // ---------------- row-copy role: direct reg copy, no LDS, no barrier -------
        const int cb = b - (ARGMIN_BLKS + HIST_BLKS + USAGE_BLKS);  // 0..31249
        const int n0 = cb * CROWS;
        const float4* src = (const float4*)(mdesc + (size_t)n0 * 256); // 1024 float4
        float* obase = out + (size_t)n0 * 259;
#pragma unroll
        for (int it = 0; it < 4; it++) {
            int g = tid + it * 256;        // 0..1023
            float4 v = src[g];
            int r = g >> 6;                // 64 float4 per 256-wide row
            int c = (g & 63) << 2;
            // dwordx4 store @ 4B alignment (addr%16==12): legal on CDNA
            *reinterpret_cast<float4*>(obase + r * 259 + 3 + c) = v;
        }
        if (tid < CROWS * 3) {
            int r = tid / 3, c = tid - r * 3;
            obase[r * 259 + c] = mpts[(size_t)n0 * 3 + tid];
        }
    }
}

// ============  FINAL: scanV + collect + sort + rank + idx + usage bump  ============
__global__ __launch_bounds__(1024) void k_final(
    const float* __restrict__ pts, const int* __restrict__ usage,
    const float* __restrict__ partKey, const int* __restrict__ partIdx,
    const int* __restrict__ histPart, float* __restrict__ out)
{
    __shared__ int      scan[1024];
    __shared__ unsigned keys[CAND_MAX];
    __shared__ int      s_cnt, s_V;
    const int t = threadIdx.x;

    // 0) reduce NSPLIT argmin partials (ascending-n chunk order: strict <)
    float bk = INFINITY; int bi = 0x7fffffff;
#pragma unroll
    for (int s = 0; s < NSPLIT; s++) {
        float k = partKey[t * NSPLIT + s];
        int   i = partIdx[t * NSPLIT + s];
        if (k < bk) { bk = k; bi = i; }
    }
    float px = pts[3*t], py = pts[3*t+1], pz = pts[3*t+2];
    float d2 = px*px + py*py + pz*pz + 2.0f * bk;
    const bool mask = d2 > 1e-6f;   // sqrt(max(d2,1e-12)) > 1e-3

    // 1) total hist + inclusive scan -> cutoff bin V
    int h = 0;
#pragma unroll
    for (int b = 0; b < HIST_BLKS; b++) h += histPart[b * 1024 + t];
    scan[t] = h;
    if (t == 0) s_cnt = 0;
    __syncthreads();
    for (int off = 1; off < 1024; off <<= 1) {
        int add = (t >= off) ? scan[t - off] : 0;
        __syncthreads();
        scan[t] += add;
        __syncthreads();
    }
    int cum  = scan[t] - h;    // count(usage < t)
    int cumN = scan[t];        // count(usage <= t)
    if (cum < M_Q && cumN >= M_Q) s_V = t;
    __syncthreads();
    const int V = s_V;

    // 2) collect candidates (usage <= V) into LDS, unordered (sort restores order)
    const int4* u4 = (const int4*)usage;
    const int TOT4 = N_TOT / 4;            // 125000
    for (int g = t; g < TOT4; g += 1024) {
        int4 u = u4[g];
        int n = g * 4;
#pragma unroll
        for (int j = 0; j < 4; j++) {
            int uv = (j == 0) ? u.x : (j == 1) ? u.y : (j == 2) ? u.z : u.w;
            if (uv <= V) {
                int p = atomicAdd(&s_cnt, 1);
                if (p < CAND_MAX) keys[p] = ((unsigned)uv << 19) | (unsigned)(n + j);
            }
        }
    }
    __syncthreads();
    int C = s_cnt; if (C > CAND_MAX) C = CAND_MAX;
    int P2 = 1; while (P2 < C) P2 <<= 1;
    for (int p = C + t; p < P2; p += 1024) keys[p] = 0xFFFFFFFFu;
    __syncthreads();

    // 3) bitonic sort ascending -> (usage asc, index asc) == lax.top_k order
    for (int k = 2; k <= P2; k <<= 1) {
        for (int j = k >> 1; j > 0; j >>= 1) {
            for (int i = t; i < P2; i += 1024) {
                int ixj = i ^ j;
                if (ixj > i) {
                    unsigned a = keys[i], bb = keys[ixj];
                    bool up = ((i & k) == 0);
                    if ((a > bb) == up) { keys[i] = bb; keys[ixj] = a; }
                }
            }
            __syncthreads();
        }
    }

    // 4) rank = cumsum(mask)-1 ; final idx; outputs (reuse scan[] for mask scan)
    scan[t] = mask ? 1 : 0; __syncthreads();
    for (int off = 1; off < 1024; off <<= 1) {
        int add = (t >= off) ? scan[t - off] : 0;
        __syncthreads();
        scan[t] += add;
        __syncthreads();
    }
    int rank = scan[t] - 1;
    int idx = mask ? (int)(keys[rank] & 0x7FFFFu) : bi;
    out[(size_t)OUT_IDX + (size_t)t] = (float)idx;
    atomicAdd(out + OUT_USAGE + idx, 1.0f);   // after mega wrote base usage
}

extern "C" void kernel_launch(void* const* d_in, const int* in_sizes, int n_in,
                              void* d_out, int out_size, void* d_ws, size_t ws_size,
                              hipStream_t stream)
{
    (void)in_sizes; (void)n_in; (void)out_size; (void)ws_size;
    const float* pts   = (const float*)d_in[0];
    const float* mpts  = (const float*)d_in[2];
    const float* mdesc = (const float*)d_in[3];
    const int*   usage = (const int*)d_in[4];
    float* out = (float*)d_out;

    char* ws = (char*)d_ws;
    float* partKey  = (float*)(ws + WS_PARTKEY);
    int*   partIdx  = (int*)(ws + WS_PARTIDX);
    int*   histPart = (int*)(ws + WS_HISTP);

    k_mega<<<MEGA_BLKS, 256, 0, stream>>>(pts, mpts, mdesc, usage, out,
                                          partKey, partIdx, histPart);
    k_final<<<1, 1024, 0, stream>>>(pts, usage, partKey, partIdx, histPart, out);
}